// Round 10
// baseline (179.675 us; speedup 1.0000x reference)
//
#include <hip/hip_runtime.h>

#define NB 8
#define NS 1024
#define ND 1024
#define NH 16
#define NHD 64

typedef __attribute__((ext_vector_type(8))) short bf16x8;
typedef __attribute__((ext_vector_type(4))) float f32x4;
typedef __attribute__((ext_vector_type(4))) unsigned int u32x4;

#define GLOAD_LDS16(g, l) __builtin_amdgcn_global_load_lds(                    \
    (const __attribute__((address_space(1))) void*)(g),                        \
    (__attribute__((address_space(3))) void*)(l), 16, 0, 0)

static __device__ __forceinline__ unsigned short f2bf(float f) {
    unsigned int u = __builtin_bit_cast(unsigned int, f);
    unsigned int r = u + 0x7fffu + ((u >> 16) & 1u);
    return (unsigned short)(r >> 16);
}

static __device__ __forceinline__ unsigned int cvtpk(float lo, float hi) {
    unsigned int r;
    asm("v_cvt_pk_bf16_f32 %0, %1, %2" : "=v"(r) : "v"(lo), "v"(hi));
    return r;
}

// ---------------- fp32 -> bf16 convert ----------------
__global__ void cvt_f32_bf16(const float* __restrict__ in, unsigned short* __restrict__ out, int n) {
    int i = (blockIdx.x * blockDim.x + threadIdx.x) * 4;
    if (i >= n) return;
    float4 v = *reinterpret_cast<const float4*>(in + i);
    ushort4 o;
    o.x = f2bf(v.x); o.y = f2bf(v.y); o.z = f2bf(v.z); o.w = f2bf(v.w);
    *reinterpret_cast<ushort4*>(out + i) = o;
}

// 3 weight matrices in one launch (grid.y selects source)
__global__ void cvt_w3(const float* __restrict__ Wq, const float* __restrict__ Wk,
                       const float* __restrict__ Wv, unsigned short* __restrict__ out) {
    const float* src = (blockIdx.y == 0) ? Wq : (blockIdx.y == 1) ? Wk : Wv;
    int i = (blockIdx.x * blockDim.x + threadIdx.x) * 4;
    float4 v = *reinterpret_cast<const float4*>(src + i);
    ushort4 o;
    o.x = f2bf(v.x); o.y = f2bf(v.y); o.z = f2bf(v.z); o.w = f2bf(v.w);
    *reinterpret_cast<ushort4*>(out + (size_t)blockIdx.y * (ND * ND) + i) = o;
}

// ---------------- QKV projection GEMM (m97-style 128x128, BK=64) ----------------
__global__ __launch_bounds__(256) void qkv_gemm(
    const unsigned short* __restrict__ A,
    const unsigned short* __restrict__ Wq, const unsigned short* __restrict__ Wk,
    const unsigned short* __restrict__ Wv,
    const float* __restrict__ bq, const float* __restrict__ bk, const float* __restrict__ bv,
    unsigned short* __restrict__ Qo, unsigned short* __restrict__ Ko, unsigned short* __restrict__ Vo)
{
    const int z = blockIdx.z;
    const unsigned short* W = (z == 0) ? Wq : (z == 1) ? Wk : Wv;
    const float* bias = (z == 0) ? bq : (z == 1) ? bk : bv;
    const int m0 = blockIdx.x * 128;
    const int n0 = blockIdx.y * 128;

    __shared__ unsigned short As[128][64];   // 16 KB, swizzled
    __shared__ unsigned short Bs[128][64];   // 16 KB, swizzled

    const int tid = threadIdx.x;
    const int lane = tid & 63;
    const int wave = tid >> 6;
    const int wm = wave >> 1, wn = wave & 1;

    f32x4 acc[4][4] = {};

    const int crow = lane >> 3;                    // row within chunk 0..7
    const int gcol = ((lane & 7) ^ crow) * 8;      // pre-swizzled source col (elems)
    const int kofs = (lane >> 4) * 8;

    for (int kb = 0; kb < ND; kb += 64) {
#pragma unroll
        for (int cc = 0; cc < 4; ++cc) {
            int c = wave * 4 + cc;                 // 16 chunks each
            GLOAD_LDS16(&A[(size_t)(m0 + c * 8 + crow) * ND + kb + gcol], &As[c * 8][0]);
            GLOAD_LDS16(&W[(size_t)(n0 + c * 8 + crow) * ND + kb + gcol], &Bs[c * 8][0]);
        }
        __syncthreads();
#pragma unroll
        for (int kk = 0; kk < 2; ++kk) {
            const int colx = (kk * 32 + kofs) ^ ((lane & 7) * 8);
            bf16x8 af[4], bfr[4];
#pragma unroll
            for (int i = 0; i < 4; ++i) {
                af[i]  = *reinterpret_cast<const bf16x8*>(&As[wm * 64 + i * 16 + (lane & 15)][colx]);
                bfr[i] = *reinterpret_cast<const bf16x8*>(&Bs[wn * 64 + i * 16 + (lane & 15)][colx]);
            }
#pragma unroll
            for (int mi = 0; mi < 4; ++mi)
#pragma unroll
                for (int ni = 0; ni < 4; ++ni)
                    acc[mi][ni] = __builtin_amdgcn_mfma_f32_16x16x32_bf16(af[mi], bfr[ni], acc[mi][ni], 0, 0, 0);
        }
        __syncthreads();
    }

#pragma unroll
    for (int ni = 0; ni < 4; ++ni) {
        int n = n0 + wn * 64 + ni * 16 + (lane & 15);
        float bv_ = bias[n];
        int h = n >> 6, hd = n & 63;
#pragma unroll
        for (int mi = 0; mi < 4; ++mi) {
            int m = m0 + wm * 64 + mi * 16 + (lane >> 4) * 4;
            int b = m >> 10, s = m & 1023;
            if (z == 2) {
                ushort4 o;
                o.x = f2bf(acc[mi][ni][0] + bv_);
                o.y = f2bf(acc[mi][ni][1] + bv_);
                o.z = f2bf(acc[mi][ni][2] + bv_);
                o.w = f2bf(acc[mi][ni][3] + bv_);
                *reinterpret_cast<ushort4*>(&Vo[(((size_t)b * NH + h) * NHD + hd) * NS + s]) = o;
            } else {
                unsigned short* O = (z == 0) ? Qo : Ko;
#pragma unroll
                for (int r2 = 0; r2 < 4; ++r2)
                    O[(((size_t)b * NH + h) * NS + s + r2) * NHD + hd] = f2bf(acc[mi][ni][r2] + bv_);
            }
        }
    }
}

// ---------------- flash attention: counted-vmcnt barrier (rel stays in flight) ----
// grid: (S/128, H, B), block 512 (8 waves). Wave owns q-rows [wave*16, +16).
// QK^T = mfma(K, Q) -> S^T: lane&15 = q, regs = kv (K row-permuted in LDS so the
// QK^T output registers coincide with the PV A-fragment; P never touches LDS).
// Per-iter sync is raw s_barrier preceded by s_waitcnt vmcnt(4) lgkmcnt(0):
// issue order is pinned {2x global_load_lds, then 4x rel loads}; vmcnt retires
// in-order, so vmcnt(4) drains exactly the LDS-bound staging while the rel
// register loads stay in flight ACROSS the barrier (full-tile latency cover).
// __syncthreads would emit vmcnt(0) and stall every tile on the rel gather.
__global__ __launch_bounds__(512) void flash_attn(
    const unsigned short* __restrict__ Q, const unsigned short* __restrict__ Kb,
    const unsigned short* __restrict__ Vt,
    const int* __restrict__ rel, const float* __restrict__ rel_emb,
    const float* __restrict__ mask, float* __restrict__ out)
{
    const int q0 = blockIdx.x * 128;
    const int h = blockIdx.y;
    const int b = blockIdx.z;
    const int tid = threadIdx.x, lane = tid & 63, wave = tid >> 6;  // wave 0..7
    const int g = lane >> 4, l15 = lane & 15;

    __shared__ unsigned short Ks[2][64][64]; // [buf][perm-kv][hd], chunk-swizzled, 16 KB
    __shared__ unsigned short Vs[2][64][64]; // [buf][hd][kv], chunk-swizzled, 16 KB
    __shared__ float s_mask[NS];             // mask[b][kv] * log2(e), 4 KB
    __shared__ float s_re2[8];               // rel_emb[.][h] * log2(e) - 4.0
    const float LOG2E = 1.4426950408889634f;
    const float SCL2 = 0.125f * 1.4426950408889634f;
    if (tid < 7) s_re2[tid] = rel_emb[tid * NH + h] * LOG2E - 4.0f;

    const unsigned short* Qh = Q  + (((size_t)b * NH + h) * NS) * NHD;
    const unsigned short* Kh = Kb + (((size_t)b * NH + h) * NS) * NHD;
    const unsigned short* Vh = Vt + (((size_t)b * NH + h) * NHD) * NS;
    const int qg = q0 + wave * 16 + l15;                 // this lane's q-row
    const int* __restrict__ relrow = rel + (size_t)b * NS * NS + (size_t)qg * NS;
    const float* __restrict__ maskb = mask + (size_t)b * NS;

    bf16x8 qa[2];
    qa[0] = *reinterpret_cast<const bf16x8*>(&Qh[(size_t)qg * NHD + g * 8]);
    qa[1] = *reinterpret_cast<const bf16x8*>(&Qh[(size_t)qg * NHD + 32 + g * 8]);

    bf16x8 vone;
#pragma unroll
    for (int i = 0; i < 8; ++i) vone[i] = (short)0x3F80;   // bf16 1.0

    f32x4 ctx[4] = {};
    f32x4 l_acc = {};
    float mofs = 0.f;            // running-max minus the folded base (4.0)
    bool everscaled = false;     // sticky, wave-uniform

    const int crow = lane >> 3;
    const int gcol = ((lane & 7) ^ crow) * 8;
    const int swz8 = (lane & 7) * 8;          // == (l15&7)*8

    // K row-permutation for staging (loop-invariant per lane):
    const int rho = wave * 8 + crow;
    const int kvperm = ((rho >> 5) << 5) + (((rho >> 2) & 3) << 3)
                     + (((rho >> 4) & 1) << 2) + (rho & 3);

#define STAGE(buf, kv)                                                                          \
    {                                                                                           \
        GLOAD_LDS16(&Kh[(size_t)((kv) + kvperm) * NHD + gcol], &Ks[buf][wave * 8][0]);          \
        GLOAD_LDS16(&Vh[(size_t)(wave * 8 + crow) * NS + (kv) + gcol], &Vs[buf][wave * 8][0]);  \
    }

    // rel codes for tile t0 -> register set S (kv of sc[tt][r] = 32*(tt>>1)+8g+4*(tt&1)+r)
#define LOADRM(S, t0)                                                           \
    {                                                                           \
        rc##S[0] = *reinterpret_cast<const int4*>(&relrow[(t0) * 64 + 8 * g]);      \
        rc##S[1] = *reinterpret_cast<const int4*>(&relrow[(t0) * 64 + 8 * g + 4]);  \
        rc##S[2] = *reinterpret_cast<const int4*>(&relrow[(t0) * 64 + 8 * g + 32]); \
        rc##S[3] = *reinterpret_cast<const int4*>(&relrow[(t0) * 64 + 8 * g + 36]); \
    }

    // counted-vmcnt barrier: drains the 2 staging gload_lds + all LDS ops,
    // leaves the (younger) rel loads in flight.
#define TILEBAR()                                              \
    {                                                          \
        asm volatile("s_waitcnt vmcnt(4) lgkmcnt(0)" ::: "memory"); \
        __builtin_amdgcn_sched_barrier(0);                     \
        __builtin_amdgcn_s_barrier();                          \
        __builtin_amdgcn_sched_barrier(0);                     \
    }

    int4 rcA[4], rcB[4];

    __builtin_amdgcn_sched_barrier(0);   // keep qa loads ahead of STAGE in the VMEM queue
    STAGE(0, 0)
    __builtin_amdgcn_sched_barrier(0);   // pin: gload_lds before rel loads
    LOADRM(A, 0)
    s_mask[tid] = maskb[tid] * LOG2E;
    s_mask[tid + 512] = maskb[tid + 512] * LOG2E;
    TILEBAR()

#define BODY(cur, S, SN, tc, tn)                                               \
  {                                                                            \
    if ((tn) < 16) {                                                           \
      STAGE(cur ^ 1, (tn) * 64)                                                \
      __builtin_amdgcn_sched_barrier(0);                                       \
      LOADRM(SN, tn)                                                           \
    }                                                                          \
    f32x4 sc[4] = {};                                                          \
    __builtin_amdgcn_s_setprio(1);                                             \
    _Pragma("unroll")                                                          \
    for (int kk = 0; kk < 2; ++kk) {                                           \
      const int colx = (kk * 32 + g * 8) ^ swz8;                               \
      _Pragma("unroll")                                                        \
      for (int tt = 0; tt < 4; ++tt) {                                         \
        bf16x8 kfrag = *reinterpret_cast<const bf16x8*>(&Ks[cur][tt * 16 + l15][colx]); \
        sc[tt] = __builtin_amdgcn_mfma_f32_16x16x32_bf16(kfrag, qa[kk], sc[tt], 0, 0, 0); \
      }                                                                        \
    }                                                                          \
    __builtin_amdgcn_s_setprio(0);                                             \
    float pmax = -1e30f;                                                       \
    _Pragma("unroll")                                                          \
    for (int tt = 0; tt < 4; ++tt) {                                           \
      float4 mv = *reinterpret_cast<const float4*>(                            \
          &s_mask[(tc) * 64 + ((tt >> 1) << 5) + 8 * g + ((tt & 1) << 2)]);    \
      const int rca[4] = {rc##S[tt].x, rc##S[tt].y, rc##S[tt].z, rc##S[tt].w}; \
      float v0 = fmaf(sc[tt][0], SCL2, s_re2[rca[0]] + mv.x);                  \
      float v1 = fmaf(sc[tt][1], SCL2, s_re2[rca[1]] + mv.y);                  \
      float v2 = fmaf(sc[tt][2], SCL2, s_re2[rca[2]] + mv.z);                  \
      float v3 = fmaf(sc[tt][3], SCL2, s_re2[rca[3]] + mv.w);                  \
      sc[tt][0] = v0; sc[tt][1] = v1; sc[tt][2] = v2; sc[tt][3] = v3;          \
      pmax = fmaxf(pmax, fmaxf(fmaxf(v0, v1), fmaxf(v2, v3)));                 \
    }                                                                          \
    if (!__all(pmax <= mofs + 8.0f)) {                                         \
      float pm = fmaxf(pmax, __shfl_xor(pmax, 16));                            \
      pm = fmaxf(pm, __shfl_xor(pm, 32));                                      \
      float mnew = fmaxf(mofs, pm);                                            \
      float alpha = exp2f(mofs - mnew);                                        \
      mofs = mnew;                                                             \
      everscaled = true;                                                       \
      float ar[4];                                                             \
      _Pragma("unroll")                                                        \
      for (int r = 0; r < 4; ++r) ar[r] = __shfl(alpha, 4 * g + r);            \
      _Pragma("unroll")                                                        \
      for (int r = 0; r < 4; ++r) l_acc[r] *= ar[r];                           \
      _Pragma("unroll")                                                        \
      for (int ht = 0; ht < 4; ++ht)                                           \
        _Pragma("unroll")                                                      \
        for (int r = 0; r < 4; ++r) ctx[ht][r] *= ar[r];                       \
    }                                                                          \
    unsigned int pw[8];                                                        \
    if (!everscaled) {                                                         \
      _Pragma("unroll")                                                        \
      for (int tt = 0; tt < 4; ++tt) {                                         \
        pw[2 * tt]     = cvtpk(exp2f(sc[tt][0]), exp2f(sc[tt][1]));            \
        pw[2 * tt + 1] = cvtpk(exp2f(sc[tt][2]), exp2f(sc[tt][3]));            \
      }                                                                        \
    } else {                                                                   \
      _Pragma("unroll")                                                        \
      for (int tt = 0; tt < 4; ++tt) {                                         \
        pw[2 * tt]     = cvtpk(exp2f(sc[tt][0] - mofs), exp2f(sc[tt][1] - mofs)); \
        pw[2 * tt + 1] = cvtpk(exp2f(sc[tt][2] - mofs), exp2f(sc[tt][3] - mofs)); \
      }                                                                        \
    }                                                                          \
    __builtin_amdgcn_s_setprio(1);                                             \
    _Pragma("unroll")                                                          \
    for (int kk = 0; kk < 2; ++kk) {                                           \
      u32x4 paw = {pw[4 * kk], pw[4 * kk + 1], pw[4 * kk + 2], pw[4 * kk + 3]};\
      bf16x8 pa = __builtin_bit_cast(bf16x8, paw);                             \
      const int colx = (kk * 32 + g * 8) ^ swz8;                               \
      l_acc = __builtin_amdgcn_mfma_f32_16x16x32_bf16(pa, vone, l_acc, 0, 0, 0); \
      _Pragma("unroll")                                                        \
      for (int ht = 0; ht < 4; ++ht) {                                         \
        bf16x8 bfrag = *reinterpret_cast<const bf16x8*>(&Vs[cur][ht * 16 + l15][colx]); \
        ctx[ht] = __builtin_amdgcn_mfma_f32_16x16x32_bf16(pa, bfrag, ctx[ht], 0, 0, 0); \
      }                                                                        \
    }                                                                          \
    __builtin_amdgcn_s_setprio(0);                                             \
    TILEBAR()                                                                  \
  }

    for (int t = 0; t < 16; t += 2) {
        BODY(0, A, B, t, t + 1)
        BODY(1, B, A, t + 1, t + 2)
    }
#undef BODY
#undef LOADRM
#undef STAGE
#undef TILEBAR

    // epilogue: l_acc is already in ctx layout (row = q_local = 4g+r)
    float linv[4];
#pragma unroll
    for (int r = 0; r < 4; ++r) linv[r] = 1.0f / l_acc[r];
#pragma unroll
    for (int ht = 0; ht < 4; ++ht) {
        int hd = ht * 16 + l15;
#pragma unroll
        for (int r = 0; r < 4; ++r) {
            int qo = q0 + wave * 16 + 4 * g + r;
            out[((size_t)b * NS + qo) * ND + h * NHD + hd] = ctx[ht][r] * linv[r];
        }
    }
}

extern "C" void kernel_launch(void* const* d_in, const int* in_sizes, int n_in,
                              void* d_out, int out_size, void* d_ws, size_t ws_size,
                              hipStream_t stream) {
    const float* hs      = (const float*)d_in[0];
    const float* mask    = (const float*)d_in[1];
    const int*   rel     = (const int*)d_in[2];
    const float* Wq      = (const float*)d_in[3];
    const float* bq      = (const float*)d_in[4];
    const float* Wk      = (const float*)d_in[5];
    const float* bk      = (const float*)d_in[6];
    const float* Wv      = (const float*)d_in[7];
    const float* bv      = (const float*)d_in[8];
    const float* rel_emb = (const float*)d_in[9];
    float* out = (float*)d_out;

    char* ws = (char*)d_ws;
    unsigned short* q_bf  = (unsigned short*)(ws);                       // 16 MB
    unsigned short* k_bf  = (unsigned short*)(ws + ((size_t)16 << 20));  // 16 MB
    unsigned short* vt_bf = (unsigned short*)(ws + ((size_t)32 << 20));  // 16 MB
    unsigned short* hs_bf = (unsigned short*)(ws + ((size_t)48 << 20));  // 16 MB
    unsigned short* w_bf  = (unsigned short*)(ws + ((size_t)64 << 20));  // 6 MB

    const int nhs = NB * NS * ND;       // 8.4M
    const int nw  = ND * ND;            // 1M
    cvt_f32_bf16<<<nhs / 4 / 256, 256, 0, stream>>>(hs, hs_bf, nhs);
    cvt_w3<<<dim3(nw / 4 / 256, 3), 256, 0, stream>>>(Wq, Wk, Wv, w_bf);

    qkv_gemm<<<dim3((NB * NS) / 128, ND / 128, 3), 256, 0, stream>>>(
        hs_bf, w_bf, w_bf + (size_t)nw, w_bf + (size_t)2 * nw,
        bq, bk, bv, q_bf, k_bf, vt_bf);

    flash_attn<<<dim3(NS / 128, NH, NB), 512, 0, stream>>>(
        q_bf, k_bf, vt_bf, rel, rel_emb, mask, out);
}

// Round 11
// 169.152 us; speedup vs baseline: 1.0622x; 1.0622x over previous
//
#include <hip/hip_runtime.h>

#define NB 8
#define NS 1024
#define ND 1024
#define NH 16
#define NHD 64

typedef __attribute__((ext_vector_type(8))) short bf16x8;
typedef __attribute__((ext_vector_type(4))) float f32x4;
typedef __attribute__((ext_vector_type(4))) unsigned int u32x4;

#define GLOAD_LDS16(g, l) __builtin_amdgcn_global_load_lds(                    \
    (const __attribute__((address_space(1))) void*)(g),                        \
    (__attribute__((address_space(3))) void*)(l), 16, 0, 0)

static __device__ __forceinline__ unsigned short f2bf(float f) {
    unsigned int u = __builtin_bit_cast(unsigned int, f);
    unsigned int r = u + 0x7fffu + ((u >> 16) & 1u);
    return (unsigned short)(r >> 16);
}

static __device__ __forceinline__ unsigned int cvtpk(float lo, float hi) {
    unsigned int r;
    asm("v_cvt_pk_bf16_f32 %0, %1, %2" : "=v"(r) : "v"(lo), "v"(hi));
    return r;
}

// ---------------- fp32 -> bf16 convert ----------------
__global__ void cvt_f32_bf16(const float* __restrict__ in, unsigned short* __restrict__ out, int n) {
    int i = (blockIdx.x * blockDim.x + threadIdx.x) * 4;
    if (i >= n) return;
    float4 v = *reinterpret_cast<const float4*>(in + i);
    ushort4 o;
    o.x = f2bf(v.x); o.y = f2bf(v.y); o.z = f2bf(v.z); o.w = f2bf(v.w);
    *reinterpret_cast<ushort4*>(out + i) = o;
}

// 3 weight matrices in one launch (grid.y selects source)
__global__ void cvt_w3(const float* __restrict__ Wq, const float* __restrict__ Wk,
                       const float* __restrict__ Wv, unsigned short* __restrict__ out) {
    const float* src = (blockIdx.y == 0) ? Wq : (blockIdx.y == 1) ? Wk : Wv;
    int i = (blockIdx.x * blockDim.x + threadIdx.x) * 4;
    float4 v = *reinterpret_cast<const float4*>(src + i);
    ushort4 o;
    o.x = f2bf(v.x); o.y = f2bf(v.y); o.z = f2bf(v.z); o.w = f2bf(v.w);
    *reinterpret_cast<ushort4*>(out + (size_t)blockIdx.y * (ND * ND) + i) = o;
}

// rel int32 -> packed int8 (4 codes per u32). Cuts the flash gather's
// L2-line amplification ~3x (two 8B chunks/row land in one 64B line).
__global__ void pack_rel8(const int* __restrict__ rel, unsigned int* __restrict__ out) {
    int i = blockIdx.x * blockDim.x + threadIdx.x;
    int4 v = reinterpret_cast<const int4*>(rel)[i];
    out[i] = (unsigned)v.x | ((unsigned)v.y << 8) | ((unsigned)v.z << 16) | ((unsigned)v.w << 24);
}

// ---------------- QKV projection GEMM (m97-style 128x128, BK=64) ----------------
// z==2 epilogue folds exp2(mask*log2e) INTO V (multiplicative mask fold):
// P*exp2(m) = exp2(s+m), so ctx uses V' = V*em and l uses an em-fragment.
__global__ __launch_bounds__(256) void qkv_gemm(
    const unsigned short* __restrict__ A,
    const unsigned short* __restrict__ Wq, const unsigned short* __restrict__ Wk,
    const unsigned short* __restrict__ Wv,
    const float* __restrict__ bq, const float* __restrict__ bk, const float* __restrict__ bv,
    const float* __restrict__ mask,
    unsigned short* __restrict__ Qo, unsigned short* __restrict__ Ko, unsigned short* __restrict__ Vo)
{
    const int z = blockIdx.z;
    const unsigned short* W = (z == 0) ? Wq : (z == 1) ? Wk : Wv;
    const float* bias = (z == 0) ? bq : (z == 1) ? bk : bv;
    const int m0 = blockIdx.x * 128;
    const int n0 = blockIdx.y * 128;
    const float LOG2E = 1.4426950408889634f;

    __shared__ unsigned short As[128][64];   // 16 KB, swizzled
    __shared__ unsigned short Bs[128][64];   // 16 KB, swizzled

    const int tid = threadIdx.x;
    const int lane = tid & 63;
    const int wave = tid >> 6;
    const int wm = wave >> 1, wn = wave & 1;

    f32x4 acc[4][4] = {};

    const int crow = lane >> 3;                    // row within chunk 0..7
    const int gcol = ((lane & 7) ^ crow) * 8;      // pre-swizzled source col (elems)
    const int kofs = (lane >> 4) * 8;

    for (int kb = 0; kb < ND; kb += 64) {
#pragma unroll
        for (int cc = 0; cc < 4; ++cc) {
            int c = wave * 4 + cc;                 // 16 chunks each
            GLOAD_LDS16(&A[(size_t)(m0 + c * 8 + crow) * ND + kb + gcol], &As[c * 8][0]);
            GLOAD_LDS16(&W[(size_t)(n0 + c * 8 + crow) * ND + kb + gcol], &Bs[c * 8][0]);
        }
        __syncthreads();
#pragma unroll
        for (int kk = 0; kk < 2; ++kk) {
            const int colx = (kk * 32 + kofs) ^ ((lane & 7) * 8);
            bf16x8 af[4], bfr[4];
#pragma unroll
            for (int i = 0; i < 4; ++i) {
                af[i]  = *reinterpret_cast<const bf16x8*>(&As[wm * 64 + i * 16 + (lane & 15)][colx]);
                bfr[i] = *reinterpret_cast<const bf16x8*>(&Bs[wn * 64 + i * 16 + (lane & 15)][colx]);
            }
#pragma unroll
            for (int mi = 0; mi < 4; ++mi)
#pragma unroll
                for (int ni = 0; ni < 4; ++ni)
                    acc[mi][ni] = __builtin_amdgcn_mfma_f32_16x16x32_bf16(af[mi], bfr[ni], acc[mi][ni], 0, 0, 0);
        }
        __syncthreads();
    }

#pragma unroll
    for (int ni = 0; ni < 4; ++ni) {
        int n = n0 + wn * 64 + ni * 16 + (lane & 15);
        float bv_ = bias[n];
        int h = n >> 6, hd = n & 63;
#pragma unroll
        for (int mi = 0; mi < 4; ++mi) {
            int m = m0 + wm * 64 + mi * 16 + (lane >> 4) * 4;
            int b = m >> 10, s = m & 1023;
            if (z == 2) {
                float4 mv = *reinterpret_cast<const float4*>(&mask[(size_t)b * NS + s]);
                ushort4 o;
                o.x = f2bf((acc[mi][ni][0] + bv_) * exp2f(mv.x * LOG2E));
                o.y = f2bf((acc[mi][ni][1] + bv_) * exp2f(mv.y * LOG2E));
                o.z = f2bf((acc[mi][ni][2] + bv_) * exp2f(mv.z * LOG2E));
                o.w = f2bf((acc[mi][ni][3] + bv_) * exp2f(mv.w * LOG2E));
                *reinterpret_cast<ushort4*>(&Vo[(((size_t)b * NH + h) * NHD + hd) * NS + s]) = o;
            } else {
                unsigned short* O = (z == 0) ? Qo : Ko;
#pragma unroll
                for (int r2 = 0; r2 < 4; ++r2)
                    O[(((size_t)b * NH + h) * NS + s + r2) * NHD + hd] = f2bf(acc[mi][ni][r2] + bv_);
            }
        }
    }
}

// ---------------- flash attention: int8 rel, mask-in-V, P in registers ----------
// grid: (S/128, H, B), block 512 (8 waves). Wave owns q-rows [wave*16, +16).
// QK^T = mfma(K, Q) -> S^T: lane&15 = q, regs = kv (K row-permuted in LDS so the
// QK^T output registers coincide with the PV A-fragment; P never touches LDS).
// rel codes arrive as packed int8 (2x dwordx2/tile, prefetched one tile ahead
// into named register sets). l = sum P*em via MFMA with an em-fragment from
// s_emask (mask folded multiplicatively; V is pre-multiplied by em in the GEMM).
__global__ __launch_bounds__(512) void flash_attn(
    const unsigned short* __restrict__ Q, const unsigned short* __restrict__ Kb,
    const unsigned short* __restrict__ Vt,
    const unsigned char* __restrict__ rel8, const float* __restrict__ rel_emb,
    const float* __restrict__ mask, float* __restrict__ out)
{
    const int q0 = blockIdx.x * 128;
    const int h = blockIdx.y;
    const int b = blockIdx.z;
    const int tid = threadIdx.x, lane = tid & 63, wave = tid >> 6;  // wave 0..7
    const int g = lane >> 4, l15 = lane & 15;

    __shared__ unsigned short Ks[2][64][64]; // [buf][perm-kv][hd], chunk-swizzled, 16 KB
    __shared__ unsigned short Vs[2][64][64]; // [buf][hd][kv], chunk-swizzled, 16 KB
    __shared__ unsigned short s_emask[NS];   // bf16 exp2(mask*log2e), 2 KB
    __shared__ float s_re2[8];               // rel_emb[.][h] * log2(e) - 4.0
    const float LOG2E = 1.4426950408889634f;
    const float SCL2 = 0.125f * 1.4426950408889634f;
    if (tid < 7) s_re2[tid] = rel_emb[tid * NH + h] * LOG2E - 4.0f;

    const unsigned short* Qh = Q  + (((size_t)b * NH + h) * NS) * NHD;
    const unsigned short* Kh = Kb + (((size_t)b * NH + h) * NS) * NHD;
    const unsigned short* Vh = Vt + (((size_t)b * NH + h) * NHD) * NS;
    const int qg = q0 + wave * 16 + l15;                 // this lane's q-row
    const unsigned char* __restrict__ relrow = rel8 + (size_t)b * NS * NS + (size_t)qg * NS;
    const float* __restrict__ maskb = mask + (size_t)b * NS;

    bf16x8 qa[2];
    qa[0] = *reinterpret_cast<const bf16x8*>(&Qh[(size_t)qg * NHD + g * 8]);
    qa[1] = *reinterpret_cast<const bf16x8*>(&Qh[(size_t)qg * NHD + 32 + g * 8]);

    f32x4 ctx[4] = {};
    f32x4 l_acc = {};
    float mofs = 0.f;            // running-max minus the folded base (4.0)
    bool everscaled = false;     // sticky, wave-uniform

    const int crow = lane >> 3;
    const int gcol = ((lane & 7) ^ crow) * 8;
    const int swz8 = (lane & 7) * 8;          // == (l15&7)*8

    // K row-permutation for staging (loop-invariant per lane):
    const int rho = wave * 8 + crow;
    const int kvperm = ((rho >> 5) << 5) + (((rho >> 2) & 3) << 3)
                     + (((rho >> 4) & 1) << 2) + (rho & 3);

#define STAGE(buf, kv)                                                                          \
    {                                                                                           \
        GLOAD_LDS16(&Kh[(size_t)((kv) + kvperm) * NHD + gcol], &Ks[buf][wave * 8][0]);          \
        GLOAD_LDS16(&Vh[(size_t)(wave * 8 + crow) * NS + (kv) + gcol], &Vs[buf][wave * 8][0]);  \
    }

    // packed rel codes for tile t0: kv = 8g..8g+7 and 32+8g..+7 -> two 8B chunks
#define LOADRM(S, t0)                                                                \
    {                                                                                \
        r##S##a = *reinterpret_cast<const uint2*>(&relrow[(t0) * 64 + 8 * g]);       \
        r##S##b = *reinterpret_cast<const uint2*>(&relrow[(t0) * 64 + 32 + 8 * g]);  \
    }

    uint2 rAa, rAb, rBa, rBb;

    STAGE(0, 0)
    LOADRM(A, 0)
    s_emask[tid] = f2bf(exp2f(maskb[tid] * LOG2E));
    s_emask[tid + 512] = f2bf(exp2f(maskb[tid + 512] * LOG2E));
    __syncthreads();

#define BODY(cur, S, SN, tc, tn)                                               \
  {                                                                            \
    if ((tn) < 16) {                                                           \
      STAGE(cur ^ 1, (tn) * 64)                                                \
      LOADRM(SN, tn)                                                           \
    }                                                                          \
    f32x4 sc[4] = {};                                                          \
    __builtin_amdgcn_s_setprio(1);                                             \
    _Pragma("unroll")                                                          \
    for (int kk = 0; kk < 2; ++kk) {                                           \
      const int colx = (kk * 32 + g * 8) ^ swz8;                               \
      _Pragma("unroll")                                                        \
      for (int tt = 0; tt < 4; ++tt) {                                         \
        bf16x8 kfrag = *reinterpret_cast<const bf16x8*>(&Ks[cur][tt * 16 + l15][colx]); \
        sc[tt] = __builtin_amdgcn_mfma_f32_16x16x32_bf16(kfrag, qa[kk], sc[tt], 0, 0, 0); \
      }                                                                        \
    }                                                                          \
    __builtin_amdgcn_s_setprio(0);                                             \
    const unsigned int rw[4] = {r##S##a.x, r##S##a.y, r##S##b.x, r##S##b.y};   \
    float pmax = -1e30f;                                                       \
    _Pragma("unroll")                                                          \
    for (int tt = 0; tt < 4; ++tt) {                                           \
      float v0 = fmaf(sc[tt][0], SCL2, s_re2[rw[tt] & 0xFF]);                  \
      float v1 = fmaf(sc[tt][1], SCL2, s_re2[(rw[tt] >> 8) & 0xFF]);           \
      float v2 = fmaf(sc[tt][2], SCL2, s_re2[(rw[tt] >> 16) & 0xFF]);          \
      float v3 = fmaf(sc[tt][3], SCL2, s_re2[rw[tt] >> 24]);                   \
      sc[tt][0] = v0; sc[tt][1] = v1; sc[tt][2] = v2; sc[tt][3] = v3;          \
      pmax = fmaxf(pmax, fmaxf(fmaxf(v0, v1), fmaxf(v2, v3)));                 \
    }                                                                          \
    if (!__all(pmax <= mofs + 8.0f)) {                                         \
      float pm = fmaxf(pmax, __shfl_xor(pmax, 16));                            \
      pm = fmaxf(pm, __shfl_xor(pm, 32));                                      \
      float mnew = fmaxf(mofs, pm);                                            \
      float alpha = exp2f(mofs - mnew);                                        \
      mofs = mnew;                                                             \
      everscaled = true;                                                       \
      float ar[4];                                                             \
      _Pragma("unroll")                                                        \
      for (int r = 0; r < 4; ++r) ar[r] = __shfl(alpha, 4 * g + r);            \
      _Pragma("unroll")                                                        \
      for (int r = 0; r < 4; ++r) l_acc[r] *= ar[r];                           \
      _Pragma("unroll")                                                        \
      for (int ht = 0; ht < 4; ++ht)                                           \
        _Pragma("unroll")                                                      \
        for (int r = 0; r < 4; ++r) ctx[ht][r] *= ar[r];                       \
    }                                                                          \
    unsigned int pw[8];                                                        \
    if (!everscaled) {                                                         \
      _Pragma("unroll")                                                        \
      for (int tt = 0; tt < 4; ++tt) {                                         \
        pw[2 * tt]     = cvtpk(exp2f(sc[tt][0]), exp2f(sc[tt][1]));            \
        pw[2 * tt + 1] = cvtpk(exp2f(sc[tt][2]), exp2f(sc[tt][3]));            \
      }                                                                        \
    } else {                                                                   \
      _Pragma("unroll")                                                        \
      for (int tt = 0; tt < 4; ++tt) {                                         \
        pw[2 * tt]     = cvtpk(exp2f(sc[tt][0] - mofs), exp2f(sc[tt][1] - mofs)); \
        pw[2 * tt + 1] = cvtpk(exp2f(sc[tt][2] - mofs), exp2f(sc[tt][3] - mofs)); \
      }                                                                        \
    }                                                                          \
    __builtin_amdgcn_s_setprio(1);                                             \
    _Pragma("unroll")                                                          \
    for (int kk = 0; kk < 2; ++kk) {                                           \
      u32x4 paw = {pw[4 * kk], pw[4 * kk + 1], pw[4 * kk + 2], pw[4 * kk + 3]};\
      bf16x8 pa = __builtin_bit_cast(bf16x8, paw);                             \
      const int colx = (kk * 32 + g * 8) ^ swz8;                               \
      bf16x8 mfr = *reinterpret_cast<const bf16x8*>(&s_emask[(tc) * 64 + kk * 32 + g * 8]); \
      l_acc = __builtin_amdgcn_mfma_f32_16x16x32_bf16(pa, mfr, l_acc, 0, 0, 0); \
      _Pragma("unroll")                                                        \
      for (int ht = 0; ht < 4; ++ht) {                                         \
        bf16x8 bfrag = *reinterpret_cast<const bf16x8*>(&Vs[cur][ht * 16 + l15][colx]); \
        ctx[ht] = __builtin_amdgcn_mfma_f32_16x16x32_bf16(pa, bfrag, ctx[ht], 0, 0, 0); \
      }                                                                        \
    }                                                                          \
    __builtin_amdgcn_s_setprio(0);                                             \
    __syncthreads();                                                           \
  }

    for (int t = 0; t < 16; t += 2) {
        BODY(0, A, B, t, t + 1)
        BODY(1, B, A, t + 1, t + 2)
    }
#undef BODY
#undef LOADRM
#undef STAGE

    // epilogue: l_acc is already in ctx layout (row = q_local = 4g+r)
    float linv[4];
#pragma unroll
    for (int r = 0; r < 4; ++r) linv[r] = 1.0f / l_acc[r];
#pragma unroll
    for (int ht = 0; ht < 4; ++ht) {
        int hd = ht * 16 + l15;
#pragma unroll
        for (int r = 0; r < 4; ++r) {
            int qo = q0 + wave * 16 + 4 * g + r;
            out[((size_t)b * NS + qo) * ND + h * NHD + hd] = ctx[ht][r] * linv[r];
        }
    }
}

extern "C" void kernel_launch(void* const* d_in, const int* in_sizes, int n_in,
                              void* d_out, int out_size, void* d_ws, size_t ws_size,
                              hipStream_t stream) {
    const float* hs      = (const float*)d_in[0];
    const float* mask    = (const float*)d_in[1];
    const int*   rel     = (const int*)d_in[2];
    const float* Wq      = (const float*)d_in[3];
    const float* bq      = (const float*)d_in[4];
    const float* Wk      = (const float*)d_in[5];
    const float* bk      = (const float*)d_in[6];
    const float* Wv      = (const float*)d_in[7];
    const float* bv      = (const float*)d_in[8];
    const float* rel_emb = (const float*)d_in[9];
    float* out = (float*)d_out;

    char* ws = (char*)d_ws;
    unsigned short* q_bf  = (unsigned short*)(ws);                       // 16 MB
    unsigned short* k_bf  = (unsigned short*)(ws + ((size_t)16 << 20));  // 16 MB
    unsigned short* vt_bf = (unsigned short*)(ws + ((size_t)32 << 20));  // 16 MB
    unsigned short* hs_bf = (unsigned short*)(ws + ((size_t)48 << 20));  // 16 MB (freed after gemm)
    unsigned short* w_bf  = (unsigned short*)(ws + ((size_t)64 << 20));  // 6 MB
    unsigned char*  rel8  = (unsigned char*)(ws + ((size_t)48 << 20));   // 8.4 MB, reuses hs_bf

    const int nhs = NB * NS * ND;       // 8.4M
    const int nw  = ND * ND;            // 1M
    cvt_f32_bf16<<<nhs / 4 / 256, 256, 0, stream>>>(hs, hs_bf, nhs);
    cvt_w3<<<dim3(nw / 4 / 256, 3), 256, 0, stream>>>(Wq, Wk, Wv, w_bf);

    qkv_gemm<<<dim3((NB * NS) / 128, ND / 128, 3), 256, 0, stream>>>(
        hs_bf, w_bf, w_bf + (size_t)nw, w_bf + (size_t)2 * nw,
        bq, bk, bv, mask, q_bf, k_bf, vt_bf);

    // hs_bf is dead after qkv_gemm; pack rel into its space
    pack_rel8<<<(NB * NS * NS / 4) / 256, 256, 0, stream>>>(rel, (unsigned int*)rel8);

    flash_attn<<<dim3(NS / 128, NH, NB), 512, 0, stream>>>(
        q_bf, k_bf, vt_bf, rel8, rel_emb, mask, out);
}